// Round 4
// baseline (123.356 us; speedup 1.0000x reference)
//
#include <hip/hip_runtime.h>

// Mutual information, N=8 images of 384x384, 50 soft bins.
// K1 hgram: fused soft-bin + batched 64x64 (padded from 50) MFMA GEMM, split-K over
//           128 slices/image; each block STORES its partial tile (no atomics).
// K2 reduce: sum 128 partial tiles per image -> hg[8][64][64] (coalesced, 16 MB).
// K3 finalize: single-block total/marginals/MI.
//
// Math: xs[b] = t_b - t_{b+1}, t_j = sigmoid(10v - 0.2j) = 1/(1 + e^{0.2j} e^{-10v}).
// One exp per element, 51 rcp. Values scaled x256 before f16 (avoids f16 denormals);
// scale cancels exactly in p = h / sum(h).
//
// R4: removed epilogue atomicAdds (R2/R3 evidence: 1.28-2.56M device-scope atomics
// onto 1250 cachelines; VALUBusy 39% / MfmaUtil 7.5% / occ 16% = latency-bound on
// the atomic drain, and doubling blocks in R3 gave ~0 net). Partials are plain
// stores; new reduce kernel does the cross-block sum at HBM rate. Memset dropped.

#define D_TOTAL   147456
#define NBATCH    8
#define BINS      50
#define KSLICES   128                      // blocks per image (split-K)
#define KC        128                      // d-columns per block iteration
#define SLICE_LEN (D_TOTAL / KSLICES)      // 1152
#define ITERS     (SLICE_LEN / KC)         // 9
#define LDS_STR   152                      // 128 + 24 f16 pad: 76 dwords = 12 mod 32

typedef _Float16 half8 __attribute__((ext_vector_type(8)));
typedef float    f32x4 __attribute__((ext_vector_type(4)));

struct Tab { float c[BINS + 1]; };
constexpr Tab make_tab() {
    Tab t{};
    double c = 1.0;
    const double lam = 1.2214027581601699;  // e^0.2
    for (int i = 0; i <= BINS; ++i) { t.c[i] = (float)c; c *= lam; }
    return t;
}
constexpr Tab TAB = make_tab();

__global__ __launch_bounds__(256, 4) void hgram_kernel(const float* __restrict__ im1,
                                                       const float* __restrict__ im2,
                                                       float* __restrict__ partial) {
    __shared__ __align__(16) _Float16 Xs[64][LDS_STR];
    __shared__ __align__(16) _Float16 Ys[64][LDS_STR];

    const int tid   = threadIdx.x;
    const int blk   = blockIdx.x;
    const int n     = blk >> 7;       // 128 slices per image
    const int slice = blk & 127;
    const int base  = n * D_TOTAL + slice * SLICE_LEN;

    // Zero LDS once (rows 50..63 stay zero; staging only rewrites rows 0..49).
    {
        unsigned* px = (unsigned*)&Xs[0][0];
        unsigned* py = (unsigned*)&Ys[0][0];
        for (int i = tid; i < 64 * LDS_STR / 2; i += 256) { px[i] = 0u; py[i] = 0u; }
    }
    __syncthreads();

    const int col = tid & 127;        // d-column within tile
    const int isY = tid >> 7;         // threads 0..127 stage X, 128..255 stage Y
    const float*  src = isY ? im2 : im1;
    _Float16*     dst = isY ? &Ys[0][0] : &Xs[0][0];

    const int lane = tid & 63;
    const int w    = tid >> 6;                 // wave id: rows [16w, 16w+16)
    const int arow = (w << 4) + (lane & 15);   // A-frag row
    const int brow = lane & 15;                // B-frag col (row of Ys)
    const int kg   = (lane >> 4) << 3;         // k sub-group offset (0,8,16,24)

    f32x4 acc0 = {0.f, 0.f, 0.f, 0.f};
    f32x4 acc1 = acc0, acc2 = acc0, acc3 = acc0;

    for (int it = 0; it < ITERS; ++it) {
        // ---- stage: one element -> 50 soft-bin weights (x256, f16) into LDS column ----
        {
            float v = src[base + it * KC + col];
            float E = __builtin_amdgcn_exp2f(v * -14.426950408889634f);   // e^{-10v}
            // t'_j = 256/(1 + c_j E) via rcp(fma(u, 1/256, 1/256))
            float tprev = __builtin_amdgcn_rcpf(__builtin_fmaf(E, 0.00390625f, 0.00390625f));
            #pragma unroll
            for (int b = 0; b < BINS; ++b) {
                float u = TAB.c[b + 1] * E;   // compile-time literal * E
                float t = __builtin_amdgcn_rcpf(__builtin_fmaf(u, 0.00390625f, 0.00390625f));
                dst[b * LDS_STR + col] = (_Float16)(tprev - t);
                tprev = t;
            }
        }
        __syncthreads();
        // ---- MFMA: this wave's 16 rows x all 64 cols, K = 128 ----
        #pragma unroll
        for (int ks = 0; ks < 4; ++ks) {
            const int k0 = ks * 32 + kg;
            half8 a  = *(const half8*)&Xs[arow][k0];
            half8 b0 = *(const half8*)&Ys[brow][k0];
            half8 b1 = *(const half8*)&Ys[16 + brow][k0];
            half8 b2 = *(const half8*)&Ys[32 + brow][k0];
            half8 b3 = *(const half8*)&Ys[48 + brow][k0];
            acc0 = __builtin_amdgcn_mfma_f32_16x16x32_f16(a, b0, acc0, 0, 0, 0);
            acc1 = __builtin_amdgcn_mfma_f32_16x16x32_f16(a, b1, acc1, 0, 0, 0);
            acc2 = __builtin_amdgcn_mfma_f32_16x16x32_f16(a, b2, acc2, 0, 0, 0);
            acc3 = __builtin_amdgcn_mfma_f32_16x16x32_f16(a, b3, acc3, 0, 0, 0);
        }
        __syncthreads();
    }

    // ---- epilogue: plain store of this block's full 64x64 partial tile ----
    float* p = partial + blk * 4096;
    const int ccol = lane & 15;
    const int rbase = (w << 4) + ((lane >> 4) << 2);
    #pragma unroll
    for (int c = 0; c < 4; ++c) {
        f32x4 a = (c == 0) ? acc0 : (c == 1) ? acc1 : (c == 2) ? acc2 : acc3;
        const int colc = c * 16 + ccol;
        #pragma unroll
        for (int r = 0; r < 4; ++r) {
            p[(rbase + r) * 64 + colc] = a[r];
        }
    }
}

// Sum the 128 partial tiles of each image: hg[n][rc] = sum_s partial[n*128+s][rc].
__global__ __launch_bounds__(256) void reduce_kernel(const float* __restrict__ partial,
                                                     float* __restrict__ hg) {
    const int idx = blockIdx.x * 256 + threadIdx.x;   // 0..32767
    const int n = idx >> 12;
    const int rc = idx & 4095;
    const float* p = partial + (size_t)n * KSLICES * 4096 + rc;
    float s = 0.f;
    #pragma unroll 8
    for (int sl = 0; sl < KSLICES; ++sl) s += p[sl * 4096];
    hg[idx] = s;
}

__global__ __launch_bounds__(1024) void finalize_kernel(const float* __restrict__ hg,
                                                        float* __restrict__ out) {
    __shared__ float red[16];
    __shared__ float marg[2][NBATCH][64];   // [0]=row sums (mx), [1]=col sums (my)
    __shared__ float sT;
    const int tid = threadIdx.x;

    // phase 1: grand total
    float s = 0.f;
    for (int i = tid; i < NBATCH * 4096; i += 1024) s += hg[i];
    #pragma unroll
    for (int o = 32; o > 0; o >>= 1) s += __shfl_down(s, o, 64);
    if ((tid & 63) == 0) red[tid >> 6] = s;
    __syncthreads();
    if (tid == 0) {
        float t = 0.f;
        for (int i = 0; i < 16; ++i) t += red[i];
        sT = t;
    }

    // phase 2: marginals — exactly 1024 tasks (8 n x 64 idx x {row,col})
    {
        const int n = tid >> 7;
        const int rem = tid & 127;
        const int which = rem >> 6;
        const int j = rem & 63;
        const float* b = hg + n * 4096;
        float m = 0.f;
        if (which == 0) { for (int c2 = 0; c2 < 64; ++c2) m += b[j * 64 + c2]; }
        else            { for (int b2 = 0; b2 < 64; ++b2) m += b[b2 * 64 + j]; }
        marg[which][n][j] = m;
    }
    __syncthreads();

    // phase 3: MI = sum p * (log(p+eps) - log(mx*my+eps)); padded entries contribute 0.
    const float invT = 1.0f / sT;
    float mi = 0.f;
    for (int i = tid; i < NBATCH * 4096; i += 1024) {
        const int n = i >> 12;
        const int rc = i & 4095;
        const int b = rc >> 6, c = rc & 63;
        const float p  = hg[i] * invT;
        const float jo = (marg[0][n][b] * invT) * (marg[1][n][c] * invT);
        mi += p * (__logf(p + 1e-8f) - __logf(jo + 1e-8f));
    }
    #pragma unroll
    for (int o = 32; o > 0; o >>= 1) mi += __shfl_down(mi, o, 64);
    if ((tid & 63) == 0) red[tid >> 6] = mi;
    __syncthreads();
    if (tid == 0) {
        float t = 0.f;
        for (int i = 0; i < 16; ++i) t += red[i];
        out[0] = t;
    }
}

extern "C" void kernel_launch(void* const* d_in, const int* in_sizes, int n_in,
                              void* d_out, int out_size, void* d_ws, size_t ws_size,
                              hipStream_t stream) {
    const float* im1 = (const float*)d_in[0];
    const float* im2 = (const float*)d_in[1];
    float* out = (float*)d_out;
    float* partial = (float*)d_ws;                       // [1024][4096] f32 = 16 MB
    float* hg = (float*)d_ws + (size_t)NBATCH * KSLICES * 4096;  // [8][4096] f32 = 128 KB

    hgram_kernel<<<dim3(NBATCH * KSLICES), dim3(256), 0, stream>>>(im1, im2, partial);
    reduce_kernel<<<dim3(NBATCH * 4096 / 256), dim3(256), 0, stream>>>(partial, hg);
    finalize_kernel<<<dim3(1), dim3(1024), 0, stream>>>(hg, out);
}

// Round 5
// 89.175 us; speedup vs baseline: 1.3833x; 1.3833x over previous
//
#include <hip/hip_runtime.h>

// Mutual information, N=8 images 384x384, 50 soft bins.
// R5 restructure: compute only the 28 EVEN sigmoid edges per element
// (j = -2,0,...,52 ; t_j = sigmoid(10v - 0.2j), scaled x256). Odd edges are a
// cubic interpolation (linear map M, err<=7.5e-5), bin差 is linear map D, so
// hgram = W G W^T with W = D*M (4-banded, coeffs {1,7,-9,1}/16 even rows,
// {-1,9,-7,-1}/16 odd rows) applied to the tiny 28x28 G in finalize.
// G[i][i'] = sum_d te_x[i,d] te_y[i',d]  -> 32x32-padded MFMA, atomic epilogue.
// Marginals telescope: sum_b W[b] = e_1 - e_26, so
//   marg_x[b] = sum_r W[b,r] (G[r,1]-G[r,26]),  T = (e1-e26) G (e1-e26)^T.

#define D_TOTAL   147456
#define NBATCH    8
#define BINS      50
#define NEDGE     28                       // even edges j=-2..52
#define KSLICES   192                      // slices per image
#define KC        128
#define SLICE_LEN (D_TOTAL / KSLICES)      // 768
#define ITERS     (SLICE_LEN / KC)         // 6
#define LDS_STR   152                      // 76 dwords = 12 mod 32: conflict-free frag reads

typedef _Float16 half8 __attribute__((ext_vector_type(8)));
typedef float    f32x4 __attribute__((ext_vector_type(4)));

__global__ __launch_bounds__(256, 6) void hgram_kernel(const float* __restrict__ im1,
                                                       const float* __restrict__ im2,
                                                       float* __restrict__ hg) {
    __shared__ __align__(16) _Float16 Xs[32][LDS_STR];
    __shared__ __align__(16) _Float16 Ys[32][LDS_STR];

    const int tid   = threadIdx.x;
    const int slice = blockIdx.x;
    const int n     = blockIdx.y;
    const int base  = n * D_TOTAL + slice * SLICE_LEN;

    {   // zero LDS once; rows 28..31 stay zero
        unsigned* px = (unsigned*)&Xs[0][0];
        unsigned* py = (unsigned*)&Ys[0][0];
        for (int i = tid; i < 32 * LDS_STR / 2; i += 256) { px[i] = 0u; py[i] = 0u; }
    }
    __syncthreads();

    const int col = tid & 127;
    const int isY = tid >> 7;
    const float*  src = isY ? im2 : im1;
    _Float16*     dst = isY ? &Ys[0][0] : &Xs[0][0];

    const int lane = tid & 63;
    const int w    = tid >> 6;
    const int r0   = (w & 1) << 4;            // G row strip (X edge)
    const int c0   = (w >> 1) << 4;           // G col strip (Y edge)
    const int frow = lane & 15;
    const int kg   = (lane >> 4) << 3;

    f32x4 acc = {0.f, 0.f, 0.f, 0.f};

    for (int it = 0; it < ITERS; ++it) {
        // ---- stage: one element -> 28 even-edge sigmoids (x256, f16) ----
        {
            float v = src[base + it * KC + col];
            float E = __builtin_amdgcn_exp2f(v * -14.426950408889634f);   // e^{-10v}
            float u = E * 0.6703200460356393f;                            // e^{-0.4}: edge j=-2
            #pragma unroll
            for (int i = 0; i < NEDGE; ++i) {
                float t = __builtin_amdgcn_rcpf(__builtin_fmaf(u, 0.00390625f, 0.00390625f));
                dst[i * LDS_STR + col] = (_Float16)t;   // 256/(1+u)
                u *= 1.4918246976412703f;               // e^{0.4} per even edge
            }
        }
        __syncthreads();
        // ---- MFMA: wave's 16x16 tile of G, K = 128 ----
        #pragma unroll
        for (int ks = 0; ks < 4; ++ks) {
            const int k0 = ks * 32 + kg;
            half8 a = *(const half8*)&Xs[r0 + frow][k0];
            half8 b = *(const half8*)&Ys[c0 + frow][k0];
            acc = __builtin_amdgcn_mfma_f32_16x16x32_f16(a, b, acc, 0, 0, 0);
        }
        __syncthreads();
    }

    // ---- epilogue: atomic-add the 28x28 region of G (stride-32 store) ----
    float* hgn = hg + n * 1024;
    const int gj = c0 + (lane & 15);
    const int ri = r0 + ((lane >> 4) << 2);
    if (gj < NEDGE) {
        #pragma unroll
        for (int r = 0; r < 4; ++r) {
            const int gi = ri + r;
            if (gi < NEDGE) atomicAdd(&hgn[gi * 32 + gj], acc[r]);
        }
    }
}

__global__ __launch_bounds__(1024) void finalize_kernel(const float* __restrict__ hg,
                                                        float* __restrict__ out) {
    __shared__ float Gs[NBATCH][NEDGE][29];   // stride 29 vs bank conflicts
    __shared__ float mx[NBATCH][BINS], my[NBATCH][BINS];
    __shared__ float red[16];
    __shared__ float sT;
    const int tid = threadIdx.x;

    for (int idx = tid; idx < NBATCH * NEDGE * NEDGE; idx += 1024) {
        int n = idx / (NEDGE * NEDGE);
        int rem = idx - n * NEDGE * NEDGE;
        int r = rem / NEDGE, c = rem - r * NEDGE;
        Gs[n][r][c] = hg[n * 1024 + r * 32 + c];
    }
    __syncthreads();

    // marginals: 800 tasks, 4-MAC band-dot each (W row applied to G*(e1-e26))
    if (tid < 2 * NBATCH * BINS) {
        const int which = (tid >= NBATCH * BINS) ? 1 : 0;
        const int t2 = which ? tid - NBATCH * BINS : tid;
        const int n = t2 / BINS, b = t2 - n * BINS;
        const int q = b >> 1;
        float w0, w1, w2, w3;
        if (b & 1) { w0 = -1.f; w1 = 9.f; w2 = -7.f; w3 = -1.f; }
        else       { w0 =  1.f; w1 = 7.f; w2 = -9.f; w3 =  1.f; }
        float m;
        if (which == 0) {
            m = w0 * (Gs[n][q][1]   - Gs[n][q][26])
              + w1 * (Gs[n][q+1][1] - Gs[n][q+1][26])
              + w2 * (Gs[n][q+2][1] - Gs[n][q+2][26])
              + w3 * (Gs[n][q+3][1] - Gs[n][q+3][26]);
            mx[n][b] = m * 0.0625f;
        } else {
            m = w0 * (Gs[n][1][q]   - Gs[n][26][q])
              + w1 * (Gs[n][1][q+1] - Gs[n][26][q+1])
              + w2 * (Gs[n][1][q+2] - Gs[n][26][q+2])
              + w3 * (Gs[n][1][q+3] - Gs[n][26][q+3]);
            my[n][b] = m * 0.0625f;
        }
    }
    if (tid == 0) {
        float t = 0.f;
        for (int n = 0; n < NBATCH; ++n)
            t += Gs[n][1][1] - Gs[n][1][26] - Gs[n][26][1] + Gs[n][26][26];
        sT = t;
    }
    __syncthreads();

    // MI pass: 2x2 entry blocks share one 4x4 G block (task = n, b-pair, c-pair)
    const float invT = 1.0f / sT;
    const float invT2 = invT * invT;
    float mi = 0.f;
    for (int task = tid; task < NBATCH * 25 * 25; task += 1024) {
        const int n = task / 625;
        const int rem = task - n * 625;
        const int bp = rem / 25, cp = rem - bp * 25;
        float g[4][4];
        #pragma unroll
        for (int r = 0; r < 4; ++r)
            #pragma unroll
            for (int s = 0; s < 4; ++s) g[r][s] = Gs[n][bp + r][cp + s];
        // row dots for even/odd c-parity
        float rde[4], rdo[4];
        #pragma unroll
        for (int r = 0; r < 4; ++r) {
            rde[r] =  g[r][0] + 7.f * g[r][1] - 9.f * g[r][2] + g[r][3];
            rdo[r] = -g[r][0] + 9.f * g[r][1] - 7.f * g[r][2] - g[r][3];
        }
        const float hee = ( rde[0] + 7.f*rde[1] - 9.f*rde[2] + rde[3]) * (1.f/256.f);
        const float heo = ( rdo[0] + 7.f*rdo[1] - 9.f*rdo[2] + rdo[3]) * (1.f/256.f);
        const float hoe = (-rde[0] + 9.f*rde[1] - 7.f*rde[2] - rde[3]) * (1.f/256.f);
        const float hoo = (-rdo[0] + 9.f*rdo[1] - 7.f*rdo[2] - rdo[3]) * (1.f/256.f);
        const int b0 = 2 * bp, c0 = 2 * cp;
        {
            float p = hee * invT, jo = mx[n][b0] * my[n][c0] * invT2;
            mi += p * (__logf(p + 1e-8f) - __logf(jo + 1e-8f));
        }
        {
            float p = heo * invT, jo = mx[n][b0] * my[n][c0 + 1] * invT2;
            mi += p * (__logf(p + 1e-8f) - __logf(jo + 1e-8f));
        }
        {
            float p = hoe * invT, jo = mx[n][b0 + 1] * my[n][c0] * invT2;
            mi += p * (__logf(p + 1e-8f) - __logf(jo + 1e-8f));
        }
        {
            float p = hoo * invT, jo = mx[n][b0 + 1] * my[n][c0 + 1] * invT2;
            mi += p * (__logf(p + 1e-8f) - __logf(jo + 1e-8f));
        }
    }
    #pragma unroll
    for (int o = 32; o > 0; o >>= 1) mi += __shfl_down(mi, o, 64);
    if ((tid & 63) == 0) red[tid >> 6] = mi;
    __syncthreads();
    if (tid == 0) {
        float t = 0.f;
        for (int i = 0; i < 16; ++i) t += red[i];
        out[0] = t;
    }
}

extern "C" void kernel_launch(void* const* d_in, const int* in_sizes, int n_in,
                              void* d_out, int out_size, void* d_ws, size_t ws_size,
                              hipStream_t stream) {
    const float* im1 = (const float*)d_in[0];
    const float* im2 = (const float*)d_in[1];
    float* out = (float*)d_out;
    float* hg  = (float*)d_ws;   // [8][32][32] f32 = 32 KB

    hipMemsetAsync(d_ws, 0, NBATCH * 1024 * sizeof(float), stream);
    hgram_kernel<<<dim3(KSLICES, NBATCH), dim3(256), 0, stream>>>(im1, im2, hg);
    finalize_kernel<<<dim3(1), dim3(1024), 0, stream>>>(hg, out);
}